// Round 1
// baseline (478.868 us; speedup 1.0000x reference)
//
#include <hip/hip_runtime.h>

#define NB 64      // batch
#define NC 32      // channels
#define PLANE 256  // 16*16
#define NK 4096    // codebook size

// ---------------- cubic (Keys a=-0.5), matches jax.image.resize 'cubic' ----
__device__ __forceinline__ float cubic_w(float x) {
    x = fabsf(x);
    if (x >= 2.f) return 0.f;
    if (x >= 1.f) return ((-0.5f * x + 2.5f) * x - 4.f) * x + 2.f;
    return ((1.5f * x - 2.5f) * x) * x + 1.f;
}

template <int PN>
__device__ __forceinline__ void taps(int o, float* w, int& i0, int& n) {
    float sf = (o + 0.5f) * ((float)PN / 16.f) - 0.5f;
    int lo = (int)floorf(sf) - 1;
    int hi = lo + 3;
    if (lo < 0) lo = 0;
    if (hi > PN - 1) hi = PN - 1;
    n = hi - lo + 1;
    i0 = lo;
    float tot = 0.f;
    for (int i = 0; i < n; i++) {
        float ww = cubic_w(sf - (float)(lo + i));
        w[i] = ww;
        tot += ww;
    }
    float inv = 1.f / tot;
    for (int i = 0; i < n; i++) w[i] *= inv;
}

// ---- exact-order helpers (match numpy reference rounding; do not touch) ----
#define FMA4(D, A, B)                                                          \
    D = __builtin_fmaf((A).x, (B).x, D); D = __builtin_fmaf((A).y, (B).y, D);  \
    D = __builtin_fmaf((A).z, (B).z, D); D = __builtin_fmaf((A).w, (B).w, D)
#define DOT32(D)                                                               \
    FMA4(D, z0, w0); FMA4(D, z1, w1); FMA4(D, z2, w2); FMA4(D, z3, w3);        \
    FMA4(D, z4, w4); FMA4(D, z5, w5); FMA4(D, z6, w6); FMA4(D, z7, w7)
// two independent token chains, interleaved per-float4 for ILP; each chain's
// own order is still the exact sequential c=0..31 fma chain.
#define DOT32_2(DA, DB)                                                        \
    FMA4(DA, a0, w0); FMA4(DB, b0, w0); FMA4(DA, a1, w1); FMA4(DB, b1, w1);    \
    FMA4(DA, a2, w2); FMA4(DB, b2, w2); FMA4(DA, a3, w3); FMA4(DB, b3, w3);    \
    FMA4(DA, a4, w4); FMA4(DB, b4, w4); FMA4(DA, a5, w5); FMA4(DB, b5, w5);    \
    FMA4(DA, a6, w6); FMA4(DB, b6, w6); FMA4(DA, a7, w7); FMA4(DB, b7, w7)

__device__ __forceinline__ float pairwise_zsq(float4 z0, float4 z1, float4 z2,
                                              float4 z3, float4 z4, float4 z5,
                                              float4 z6, float4 z7) {
#define SQ_(a) __fmul_rn((a), (a))
#define R4_(a, b, c, d) \
    __fadd_rn(__fadd_rn(__fadd_rn(SQ_(a), SQ_(b)), SQ_(c)), SQ_(d))
    float r0 = R4_(z0.x, z2.x, z4.x, z6.x);
    float r1 = R4_(z0.y, z2.y, z4.y, z6.y);
    float r2 = R4_(z0.z, z2.z, z4.z, z6.z);
    float r3 = R4_(z0.w, z2.w, z4.w, z6.w);
    float r4 = R4_(z1.x, z3.x, z5.x, z7.x);
    float r5 = R4_(z1.y, z3.y, z5.y, z7.y);
    float r6 = R4_(z1.z, z3.z, z5.z, z7.z);
    float r7 = R4_(z1.w, z3.w, z5.w, z7.w);
    return __fadd_rn(__fadd_rn(__fadd_rn(r0, r1), __fadd_rn(r2, r3)),
                     __fadd_rn(__fadd_rn(r4, r5), __fadd_rn(r6, r7)));
#undef R4_
#undef SQ_
}

// ---------------- init: plane means of z_enc -> zflat0 ; ||e||^2 -----------
__global__ void __launch_bounds__(256) init_kernel(
    const float* __restrict__ z_enc, const float* __restrict__ emb,
    float* __restrict__ zflat0, float* __restrict__ wsq) {
    int bc = blockIdx.x;
    int t = threadIdx.x;
    float v = z_enc[bc * PLANE + t];
    for (int o = 32; o > 0; o >>= 1) v += __shfl_down(v, o, 64);
    __shared__ float p[4];
    if ((t & 63) == 0) p[t >> 6] = v;
    __syncthreads();
    if (t == 0) zflat0[bc] = (p[0] + p[1] + p[2] + p[3]) * (1.f / 256.f);
    if (t < 64) {
        int k = 2 * bc + (t >> 5);
        int c = t & 31;
        float e = emb[k * 32 + c];
        float s = __fmul_rn(e, e);
        for (int o = 16; o > 0; o >>= 1) s += __shfl_down(s, o, 32);
        if (c == 0) wsq[k] = s;
    }
}

// ---------------- token-parallel argmin partial, 2 tokens/lane --------------
// 1 wave = 128 tokens (lane handles tok and tok+64); k-loop wave-uniform ->
// emb rows come in as s_loads, amortized over 2 tokens (64 FMA per 132 B of
// scalar traffic). Each token's dot is the exact sequential fp32 fma chain
// (c=0..31) like the numpy reference -> same rounding grid, same ties.
template <int CPK>
__global__ void __launch_bounds__(64, 4) part2_kernel(
    const float* __restrict__ zflat, const float* __restrict__ emb,
    const float* __restrict__ wsq, float* __restrict__ cand_d,
    int* __restrict__ cand_i, int T) {
    int tokA = blockIdx.x * 128 + threadIdx.x;
    int tokB = tokA + 64;
    int k0 = blockIdx.y * CPK;
    const float4* za = (const float4*)(zflat + (size_t)tokA * 32);
    const float4* zb = (const float4*)(zflat + (size_t)tokB * 32);
    float4 a0 = za[0], a1 = za[1], a2 = za[2], a3 = za[3];
    float4 a4 = za[4], a5 = za[5], a6 = za[6], a7 = za[7];
    float4 b0 = zb[0], b1 = zb[1], b2 = zb[2], b3 = zb[3];
    float4 b4 = zb[4], b5 = zb[5], b6 = zb[6], b7 = zb[7];
    float zsqA = pairwise_zsq(a0, a1, a2, a3, a4, a5, a6, a7);
    float zsqB = pairwise_zsq(b0, b1, b2, b3, b4, b5, b6, b7);

    float bestA = 1e30f, bestB = 1e30f;
    int biA = 0, biB = 0;
#pragma unroll 2
    for (int k = k0; k < k0 + CPK; k++) {
        const float4* wr = (const float4*)emb + (size_t)k * 8;  // uniform
        float4 w0 = wr[0], w1 = wr[1], w2 = wr[2], w3 = wr[3];
        float4 w4 = wr[4], w5 = wr[5], w6 = wr[6], w7 = wr[7];
        float wk = wsq[k];
        float dotA = 0.f, dotB = 0.f;
        DOT32_2(dotA, dotB);
        float dA = __fsub_rn(__fadd_rn(zsqA, wk), __fmul_rn(2.f, dotA));
        float dB = __fsub_rn(__fadd_rn(zsqB, wk), __fmul_rn(2.f, dotB));
        if (dA < bestA) { bestA = dA; biA = k; }  // strict < keeps lowest k
        if (dB < bestB) { bestB = dB; biB = k; }
    }
    cand_d[(size_t)blockIdx.y * T + tokA] = bestA;
    cand_i[(size_t)blockIdx.y * T + tokA] = biA;
    cand_d[(size_t)blockIdx.y * T + tokB] = bestB;
    cand_i[(size_t)blockIdx.y * T + tokB] = biB;
}

// ---------------- k-parallel argmin partial (small T: levels 0,1) -----------
// 1 wave = 1 token x 64*KPL codes; lane L handles k = kbase + j*64 + L.
// Same exact per-k dist; wave shuffle-reduce of lexicographic (d, k) min.
template <int KPL>
__global__ void __launch_bounds__(64, 4) partk_kernel(
    const float* __restrict__ zflat, const float* __restrict__ emb,
    const float* __restrict__ wsq, float* __restrict__ cand_d,
    int* __restrict__ cand_i, int T) {
    int tok = blockIdx.x;
    int lane = threadIdx.x;
    int kbase = blockIdx.y * (KPL * 64);
    const float4* zr = (const float4*)(zflat + (size_t)tok * 32);
    float4 z0 = zr[0], z1 = zr[1], z2 = zr[2], z3 = zr[3];
    float4 z4 = zr[4], z5 = zr[5], z6 = zr[6], z7 = zr[7];
    float zsq = pairwise_zsq(z0, z1, z2, z3, z4, z5, z6, z7);

    float best = 1e30f;
    int bi = 0;
#pragma unroll
    for (int j = 0; j < KPL; j++) {
        int k = kbase + j * 64 + lane;   // ascending per lane
        const float4* wr = (const float4*)emb + (size_t)k * 8;  // per-lane
        float4 w0 = wr[0], w1 = wr[1], w2 = wr[2], w3 = wr[3];
        float4 w4 = wr[4], w5 = wr[5], w6 = wr[6], w7 = wr[7];
        float dot = 0.f;
        DOT32(dot);
        float d = __fsub_rn(__fadd_rn(zsq, wsq[k]), __fmul_rn(2.f, dot));
        if (d < best) { best = d; bi = k; }
    }
    // lexicographic (d, k) min across the wave (first-index tie-break)
    for (int off = 32; off > 0; off >>= 1) {
        float od = __shfl_down(best, off, 64);
        int oi = __shfl_down(bi, off, 64);
        if (od < best || (od == best && oi < bi)) { best = od; bi = oi; }
    }
    if (lane == 0) {
        cand_d[(size_t)blockIdx.y * T + tok] = best;
        cand_i[(size_t)blockIdx.y * T + tok] = bi;
    }
}

// ---------------- combine2: one thread per TOKEN (not token x channel) ------
// Serial ascending lex-min over KS chunks (identical winner/tie rule as
// before), then vectorized 128 B copy of the winning code row.
__global__ void __launch_bounds__(256) combine_kernel(
    const float* __restrict__ cand_d, const int* __restrict__ cand_i,
    const float* __restrict__ emb, float* __restrict__ zq, int T, int KS) {
    int tok = blockIdx.x * 256 + threadIdx.x;
    if (tok >= T) return;
    float best = 1e30f;
    int bi = 0x7fffffff;
    for (int s = 0; s < KS; s++) {
        float d = cand_d[(size_t)s * T + tok];
        int i = cand_i[(size_t)s * T + tok];
        if (d < best || (d == best && i < bi)) { best = d; bi = i; }
    }
    const float4* er = (const float4*)emb + (size_t)bi * 8;
    float4* zr = (float4*)zq + (size_t)tok * 8;
#pragma unroll
    for (int q = 0; q < 8; q++) zr[q] = er[q];
}

// ---------------- apply: upsample + accumulate out + successive z_rest ------
template <int PN, int PN_NEXT>
__global__ void __launch_bounds__(256) apply_kernel(
    const float* __restrict__ zrest_in, const float* __restrict__ zq,
    float* __restrict__ out_lvl, const float* __restrict__ out_prev,
    float* __restrict__ zrest_out, float* __restrict__ zflat_next) {
    __shared__ float rest[PLANE];
    int bc = blockIdx.x;
    int b = bc >> 5, c = bc & 31;
    int t = threadIdx.x;
    int h = t >> 4, w = t & 15;

    float zup;
    if constexpr (PN == 16) {
        zup = zq[(size_t)(((b * 16 + h) * 16 + w)) * 32 + c];
    } else {
        float wy[4], wx[4];
        int iy0, ny, jx0, nx;
        taps<PN>(h, wy, iy0, ny);
        taps<PN>(w, wx, jx0, nx);
        zup = 0.f;
        for (int e = 0; e < nx; e++) {
            float colacc = 0.f;
            for (int a = 0; a < ny; a++)
                colacc += wy[a] * zq[(size_t)((b * PN + iy0 + a) * PN + (jx0 + e)) * 32 + c];
            zup += wx[e] * colacc;
        }
    }
    int idx = bc * PLANE + t;
    float prev = out_prev ? out_prev[idx] : 0.f;
    out_lvl[idx] = __fadd_rn(prev, zup);

    if (zflat_next) {
        float rv = __fsub_rn(zrest_in[idx], zup);
        rest[t] = rv;
        if (zrest_out) zrest_out[idx] = rv;
        __syncthreads();
        constexpr int S = 16 / PN_NEXT;
        if (t < PN_NEXT * PN_NEXT) {
            int i = t / PN_NEXT, j = t % PN_NEXT;
            float s = 0.f;
            for (int di = 0; di < S; di++)
                for (int dj = 0; dj < S; dj++)
                    s = __fadd_rn(s, rest[(i * S + di) * 16 + (j * S + dj)]);
            zflat_next[(size_t)((b * PN_NEXT + i) * PN_NEXT + j) * 32 + c] =
                s * (1.f / (float)(S * S));
        }
    }
}

extern "C" void kernel_launch(void* const* d_in, const int* in_sizes, int n_in,
                              void* d_out, int out_size, void* d_ws, size_t ws_size,
                              hipStream_t stream) {
    const float* z_enc = (const float*)d_in[0];   // [64,32,16,16]
    const float* emb   = (const float*)d_in[1];   // [4096,32]
    float* out = (float*)d_out;                   // [5,64,32,16,16]
    float* ws = (float*)d_ws;

    float* wsq    = ws;                       // 4096
    float* zflat  = wsq + NK;                 // 524288 (token-major, C-last)
    float* zq     = zflat + 524288;           // 524288
    float* zrest  = zq + 524288;              // 524288 (plane layout)
    float* cand_d = zrest + 524288;           // 524288
    int*   cand_i = (int*)(cand_d + 524288);  // 524288

    const int LVL = NB * NC * PLANE;  // 524288 elems per output level

    init_kernel<<<2048, 256, 0, stream>>>(z_enc, emb, zflat, wsq);

    // level 0: T=64, k-parallel: 16 chunks x 256 codes -> 1024 waves
    partk_kernel<4><<<dim3(64, 16), 64, 0, stream>>>(zflat, emb, wsq, cand_d, cand_i, 64);
    combine_kernel<<<1, 256, 0, stream>>>(cand_d, cand_i, emb, zq, 64, 16);
    apply_kernel<1, 2><<<2048, 256, 0, stream>>>(z_enc, zq, out, nullptr, zrest, zflat);

    // level 1: T=256, k-parallel: 4096 waves
    partk_kernel<4><<<dim3(256, 16), 64, 0, stream>>>(zflat, emb, wsq, cand_d, cand_i, 256);
    combine_kernel<<<1, 256, 0, stream>>>(cand_d, cand_i, emb, zq, 256, 16);
    apply_kernel<2, 4><<<2048, 256, 0, stream>>>(zrest, zq, out + LVL, out, zrest, zflat);

    // level 2: T=1024, 2-tok token-parallel: KS=512, CPK=8 -> 4096 waves
    part2_kernel<8><<<dim3(8, 512), 64, 0, stream>>>(zflat, emb, wsq, cand_d, cand_i, 1024);
    combine_kernel<<<4, 256, 0, stream>>>(cand_d, cand_i, emb, zq, 1024, 512);
    apply_kernel<4, 8><<<2048, 256, 0, stream>>>(zrest, zq, out + 2 * LVL, out + LVL, zrest, zflat);

    // level 3: T=4096, KS=128, CPK=32 -> 4096 waves
    part2_kernel<32><<<dim3(32, 128), 64, 0, stream>>>(zflat, emb, wsq, cand_d, cand_i, 4096);
    combine_kernel<<<16, 256, 0, stream>>>(cand_d, cand_i, emb, zq, 4096, 128);
    apply_kernel<8, 16><<<2048, 256, 0, stream>>>(zrest, zq, out + 3 * LVL, out + 2 * LVL, zrest, zflat);

    // level 4: T=16384, KS=32, CPK=128 -> 4096 waves (8 chains/SIMD of ILP)
    part2_kernel<128><<<dim3(128, 32), 64, 0, stream>>>(zflat, emb, wsq, cand_d, cand_i, 16384);
    combine_kernel<<<64, 256, 0, stream>>>(cand_d, cand_i, emb, zq, 16384, 32);
    apply_kernel<16, 16><<<2048, 256, 0, stream>>>(zrest, zq, out + 4 * LVL, out + 3 * LVL, nullptr, nullptr);
}

// Round 3
// 247.478 us; speedup vs baseline: 1.9350x; 1.9350x over previous
//
#include <hip/hip_runtime.h>

#define NB 64      // batch
#define NC 32      // channels
#define PLANE 256  // 16*16
#define NK 4096    // codebook size

// ---------------- cubic (Keys a=-0.5), matches jax.image.resize 'cubic' ----
__device__ __forceinline__ float cubic_w(float x) {
    x = fabsf(x);
    if (x >= 2.f) return 0.f;
    if (x >= 1.f) return ((-0.5f * x + 2.5f) * x - 4.f) * x + 2.f;
    return ((1.5f * x - 2.5f) * x) * x + 1.f;
}

template <int PN>
__device__ __forceinline__ void taps(int o, float* w, int& i0, int& n) {
    float sf = (o + 0.5f) * ((float)PN / 16.f) - 0.5f;
    int lo = (int)floorf(sf) - 1;
    int hi = lo + 3;
    if (lo < 0) lo = 0;
    if (hi > PN - 1) hi = PN - 1;
    n = hi - lo + 1;
    i0 = lo;
    float tot = 0.f;
    for (int i = 0; i < n; i++) {
        float ww = cubic_w(sf - (float)(lo + i));
        w[i] = ww;
        tot += ww;
    }
    float inv = 1.f / tot;
    for (int i = 0; i < n; i++) w[i] *= inv;
}

// ---- exact-order helpers (match numpy reference rounding; do not touch) ----
#define FMA4(D, A, B)                                                          \
    D = __builtin_fmaf((A).x, (B).x, D); D = __builtin_fmaf((A).y, (B).y, D);  \
    D = __builtin_fmaf((A).z, (B).z, D); D = __builtin_fmaf((A).w, (B).w, D)
#define DOT32(D)                                                               \
    FMA4(D, z0, w0); FMA4(D, z1, w1); FMA4(D, z2, w2); FMA4(D, z3, w3);        \
    FMA4(D, z4, w4); FMA4(D, z5, w5); FMA4(D, z6, w6); FMA4(D, z7, w7)
// two independent token chains, interleaved per-float4 for ILP; each chain's
// own order is still the exact sequential c=0..31 fma chain.
#define DOT32_2(DA, DB)                                                        \
    FMA4(DA, a0, w0); FMA4(DB, b0, w0); FMA4(DA, a1, w1); FMA4(DB, b1, w1);    \
    FMA4(DA, a2, w2); FMA4(DB, b2, w2); FMA4(DA, a3, w3); FMA4(DB, b3, w3);    \
    FMA4(DA, a4, w4); FMA4(DB, b4, w4); FMA4(DA, a5, w5); FMA4(DB, b5, w5);    \
    FMA4(DA, a6, w6); FMA4(DB, b6, w6); FMA4(DA, a7, w7); FMA4(DB, b7, w7)

__device__ __forceinline__ float pairwise_zsq(float4 z0, float4 z1, float4 z2,
                                              float4 z3, float4 z4, float4 z5,
                                              float4 z6, float4 z7) {
#define SQ_(a) __fmul_rn((a), (a))
#define R4_(a, b, c, d) \
    __fadd_rn(__fadd_rn(__fadd_rn(SQ_(a), SQ_(b)), SQ_(c)), SQ_(d))
    float r0 = R4_(z0.x, z2.x, z4.x, z6.x);
    float r1 = R4_(z0.y, z2.y, z4.y, z6.y);
    float r2 = R4_(z0.z, z2.z, z4.z, z6.z);
    float r3 = R4_(z0.w, z2.w, z4.w, z6.w);
    float r4 = R4_(z1.x, z3.x, z5.x, z7.x);
    float r5 = R4_(z1.y, z3.y, z5.y, z7.y);
    float r6 = R4_(z1.z, z3.z, z5.z, z7.z);
    float r7 = R4_(z1.w, z3.w, z5.w, z7.w);
    return __fadd_rn(__fadd_rn(__fadd_rn(r0, r1), __fadd_rn(r2, r3)),
                     __fadd_rn(__fadd_rn(r4, r5), __fadd_rn(r6, r7)));
#undef R4_
#undef SQ_
}

// ---------------- init: plane means of z_enc -> zflat0 ; ||e||^2 -----------
__global__ void __launch_bounds__(256) init_kernel(
    const float* __restrict__ z_enc, const float* __restrict__ emb,
    float* __restrict__ zflat0, float* __restrict__ wsq) {
    int bc = blockIdx.x;
    int t = threadIdx.x;
    float v = z_enc[bc * PLANE + t];
    for (int o = 32; o > 0; o >>= 1) v += __shfl_down(v, o, 64);
    __shared__ float p[4];
    if ((t & 63) == 0) p[t >> 6] = v;
    __syncthreads();
    if (t == 0) zflat0[bc] = (p[0] + p[1] + p[2] + p[3]) * (1.f / 256.f);
    if (t < 64) {
        int k = 2 * bc + (t >> 5);
        int c = t & 31;
        float e = emb[k * 32 + c];
        float s = __fmul_rn(e, e);
        for (int o = 16; o > 0; o >>= 1) s += __shfl_down(s, o, 32);
        if (c == 0) wsq[k] = s;
    }
}

// ---------------- token-parallel argmin partial, 2 tokens/lane --------------
// 1 wave = 128 tokens (lane handles tok and tok+64); k-loop wave-uniform ->
// emb rows come in as s_loads, amortized over 2 tokens (64 FMA per 132 B of
// scalar traffic). Each token's dot is the exact sequential fp32 fma chain
// (c=0..31) like the numpy reference -> same rounding grid, same ties.
// Candidates written TRANSPOSED: cand[tok*KS + chunk] so the combine reads
// a token's candidates contiguously (KS = gridDim.y).
template <int CPK>
__global__ void __launch_bounds__(64, 4) part2_kernel(
    const float* __restrict__ zflat, const float* __restrict__ emb,
    const float* __restrict__ wsq, float* __restrict__ cand_d,
    int* __restrict__ cand_i, int T) {
    int tokA = blockIdx.x * 128 + threadIdx.x;
    int tokB = tokA + 64;
    int KS = gridDim.y;
    int k0 = blockIdx.y * CPK;
    const float4* za = (const float4*)(zflat + (size_t)tokA * 32);
    const float4* zb = (const float4*)(zflat + (size_t)tokB * 32);
    float4 a0 = za[0], a1 = za[1], a2 = za[2], a3 = za[3];
    float4 a4 = za[4], a5 = za[5], a6 = za[6], a7 = za[7];
    float4 b0 = zb[0], b1 = zb[1], b2 = zb[2], b3 = zb[3];
    float4 b4 = zb[4], b5 = zb[5], b6 = zb[6], b7 = zb[7];
    float zsqA = pairwise_zsq(a0, a1, a2, a3, a4, a5, a6, a7);
    float zsqB = pairwise_zsq(b0, b1, b2, b3, b4, b5, b6, b7);

    float bestA = 1e30f, bestB = 1e30f;
    int biA = 0, biB = 0;
#pragma unroll 2
    for (int k = k0; k < k0 + CPK; k++) {
        const float4* wr = (const float4*)emb + (size_t)k * 8;  // uniform
        float4 w0 = wr[0], w1 = wr[1], w2 = wr[2], w3 = wr[3];
        float4 w4 = wr[4], w5 = wr[5], w6 = wr[6], w7 = wr[7];
        float wk = wsq[k];
        float dotA = 0.f, dotB = 0.f;
        DOT32_2(dotA, dotB);
        float dA = __fsub_rn(__fadd_rn(zsqA, wk), __fmul_rn(2.f, dotA));
        float dB = __fsub_rn(__fadd_rn(zsqB, wk), __fmul_rn(2.f, dotB));
        if (dA < bestA) { bestA = dA; biA = k; }  // strict < keeps lowest k
        if (dB < bestB) { bestB = dB; biB = k; }
    }
    cand_d[(size_t)tokA * KS + blockIdx.y] = bestA;
    cand_i[(size_t)tokA * KS + blockIdx.y] = biA;
    cand_d[(size_t)tokB * KS + blockIdx.y] = bestB;
    cand_i[(size_t)tokB * KS + blockIdx.y] = biB;
}

// ---------------- k-parallel argmin partial (small T: levels 0,1) -----------
// 1 wave = 1 token x 64*KPL codes; lane L handles k = kbase + j*64 + L.
// Same exact per-k dist; wave shuffle-reduce of lexicographic (d, k) min.
// Transposed candidate write (cand[tok*KS + chunk]).
template <int KPL>
__global__ void __launch_bounds__(64, 4) partk_kernel(
    const float* __restrict__ zflat, const float* __restrict__ emb,
    const float* __restrict__ wsq, float* __restrict__ cand_d,
    int* __restrict__ cand_i, int T) {
    int tok = blockIdx.x;
    int lane = threadIdx.x;
    int KS = gridDim.y;
    int kbase = blockIdx.y * (KPL * 64);
    const float4* zr = (const float4*)(zflat + (size_t)tok * 32);
    float4 z0 = zr[0], z1 = zr[1], z2 = zr[2], z3 = zr[3];
    float4 z4 = zr[4], z5 = zr[5], z6 = zr[6], z7 = zr[7];
    float zsq = pairwise_zsq(z0, z1, z2, z3, z4, z5, z6, z7);

    float best = 1e30f;
    int bi = 0;
#pragma unroll
    for (int j = 0; j < KPL; j++) {
        int k = kbase + j * 64 + lane;   // ascending per lane
        const float4* wr = (const float4*)emb + (size_t)k * 8;  // per-lane
        float4 w0 = wr[0], w1 = wr[1], w2 = wr[2], w3 = wr[3];
        float4 w4 = wr[4], w5 = wr[5], w6 = wr[6], w7 = wr[7];
        float dot = 0.f;
        DOT32(dot);
        float d = __fsub_rn(__fadd_rn(zsq, wsq[k]), __fmul_rn(2.f, dot));
        if (d < best) { best = d; bi = k; }
    }
    // lexicographic (d, k) min across the wave (first-index tie-break)
    for (int off = 32; off > 0; off >>= 1) {
        float od = __shfl_down(best, off, 64);
        int oi = __shfl_down(bi, off, 64);
        if (od < best || (od == best && oi < bi)) { best = od; bi = oi; }
    }
    if (lane == 0) {
        cand_d[(size_t)tok * KS + blockIdx.y] = best;
        cand_i[(size_t)tok * KS + blockIdx.y] = bi;
    }
}

// ---------------- combine_wave: one 64-lane wave per token ------------------
// Lane l lex-reduces chunks s = l, l+64, ...; shuffle lex-min across the wave
// (associative -> same winner/tie-break as the serial ascending scan); then
// lanes 0-7 copy the winning 128 B code row. Candidate reads are contiguous
// per token thanks to the [tok][s] layout.
__global__ void __launch_bounds__(256) combine_wave(
    const float* __restrict__ cand_d, const int* __restrict__ cand_i,
    const float* __restrict__ emb, float* __restrict__ zq, int T, int KS) {
    int tok = (blockIdx.x * 256 + threadIdx.x) >> 6;
    int lane = threadIdx.x & 63;
    if (tok >= T) return;
    float best = 1e30f;
    int bi = 0x7fffffff;
    for (int s = lane; s < KS; s += 64) {
        float d = cand_d[(size_t)tok * KS + s];
        int i = cand_i[(size_t)tok * KS + s];
        if (d < best || (d == best && i < bi)) { best = d; bi = i; }
    }
    for (int off = 32; off > 0; off >>= 1) {
        float od = __shfl_down(best, off, 64);
        int oi = __shfl_down(bi, off, 64);
        if (od < best || (od == best && oi < bi)) { best = od; bi = oi; }
    }
    bi = __shfl(bi, 0, 64);
    if (lane < 8) {
        ((float4*)zq)[(size_t)tok * 8 + lane] =
            ((const float4*)emb)[(size_t)bi * 8 + lane];
    }
}

// ---------------- apply: upsample + accumulate out + successive z_rest ------
template <int PN, int PN_NEXT>
__global__ void __launch_bounds__(256) apply_kernel(
    const float* __restrict__ zrest_in, const float* __restrict__ zq,
    float* __restrict__ out_lvl, const float* __restrict__ out_prev,
    float* __restrict__ zrest_out, float* __restrict__ zflat_next) {
    __shared__ float rest[PLANE];
    int bc = blockIdx.x;
    int b = bc >> 5, c = bc & 31;
    int t = threadIdx.x;
    int h = t >> 4, w = t & 15;

    float zup;
    if constexpr (PN == 16) {
        zup = zq[(size_t)(((b * 16 + h) * 16 + w)) * 32 + c];
    } else {
        float wy[4], wx[4];
        int iy0, ny, jx0, nx;
        taps<PN>(h, wy, iy0, ny);
        taps<PN>(w, wx, jx0, nx);
        zup = 0.f;
        for (int e = 0; e < nx; e++) {
            float colacc = 0.f;
            for (int a = 0; a < ny; a++)
                colacc += wy[a] * zq[(size_t)((b * PN + iy0 + a) * PN + (jx0 + e)) * 32 + c];
            zup += wx[e] * colacc;
        }
    }
    int idx = bc * PLANE + t;
    float prev = out_prev ? out_prev[idx] : 0.f;
    out_lvl[idx] = __fadd_rn(prev, zup);

    if (zflat_next) {
        float rv = __fsub_rn(zrest_in[idx], zup);
        rest[t] = rv;
        if (zrest_out) zrest_out[idx] = rv;
        __syncthreads();
        constexpr int S = 16 / PN_NEXT;
        if (t < PN_NEXT * PN_NEXT) {
            int i = t / PN_NEXT, j = t % PN_NEXT;
            float s = 0.f;
            for (int di = 0; di < S; di++)
                for (int dj = 0; dj < S; dj++)
                    s = __fadd_rn(s, rest[(i * S + di) * 16 + (j * S + dj)]);
            zflat_next[(size_t)((b * PN_NEXT + i) * PN_NEXT + j) * 32 + c] =
                s * (1.f / (float)(S * S));
        }
    }
}

extern "C" void kernel_launch(void* const* d_in, const int* in_sizes, int n_in,
                              void* d_out, int out_size, void* d_ws, size_t ws_size,
                              hipStream_t stream) {
    const float* z_enc = (const float*)d_in[0];   // [64,32,16,16]
    const float* emb   = (const float*)d_in[1];   // [4096,32]
    float* out = (float*)d_out;                   // [5,64,32,16,16]
    float* ws = (float*)d_ws;

    float* wsq    = ws;                       // 4096
    float* zflat  = wsq + NK;                 // 524288 (token-major, C-last)
    float* zq     = zflat + 524288;           // 524288
    float* zrest  = zq + 524288;              // 524288 (plane layout)
    float* cand_d = zrest + 524288;           // 524288 ([tok][s] layout)
    int*   cand_i = (int*)(cand_d + 524288);  // 524288

    const int LVL = NB * NC * PLANE;  // 524288 elems per output level

    init_kernel<<<2048, 256, 0, stream>>>(z_enc, emb, zflat, wsq);

    // level 0: T=64, k-parallel: 16 chunks x 256 codes -> 1024 waves
    partk_kernel<4><<<dim3(64, 16), 64, 0, stream>>>(zflat, emb, wsq, cand_d, cand_i, 64);
    combine_wave<<<16, 256, 0, stream>>>(cand_d, cand_i, emb, zq, 64, 16);
    apply_kernel<1, 2><<<2048, 256, 0, stream>>>(z_enc, zq, out, nullptr, zrest, zflat);

    // level 1: T=256, k-parallel: 4096 waves
    partk_kernel<4><<<dim3(256, 16), 64, 0, stream>>>(zflat, emb, wsq, cand_d, cand_i, 256);
    combine_wave<<<64, 256, 0, stream>>>(cand_d, cand_i, emb, zq, 256, 16);
    apply_kernel<2, 4><<<2048, 256, 0, stream>>>(zrest, zq, out + LVL, out, zrest, zflat);

    // level 2: T=1024, 2-tok token-parallel: KS=512, CPK=8 -> 4096 waves
    part2_kernel<8><<<dim3(8, 512), 64, 0, stream>>>(zflat, emb, wsq, cand_d, cand_i, 1024);
    combine_wave<<<256, 256, 0, stream>>>(cand_d, cand_i, emb, zq, 1024, 512);
    apply_kernel<4, 8><<<2048, 256, 0, stream>>>(zrest, zq, out + 2 * LVL, out + LVL, zrest, zflat);

    // level 3: T=4096, KS=128, CPK=32 -> 4096 waves
    part2_kernel<32><<<dim3(32, 128), 64, 0, stream>>>(zflat, emb, wsq, cand_d, cand_i, 4096);
    combine_wave<<<1024, 256, 0, stream>>>(cand_d, cand_i, emb, zq, 4096, 128);
    apply_kernel<8, 16><<<2048, 256, 0, stream>>>(zrest, zq, out + 3 * LVL, out + 2 * LVL, zrest, zflat);

    // level 4: T=16384, KS=32, CPK=128 -> 4096 waves (8 chains/SIMD of ILP)
    part2_kernel<128><<<dim3(128, 32), 64, 0, stream>>>(zflat, emb, wsq, cand_d, cand_i, 16384);
    combine_wave<<<4096, 256, 0, stream>>>(cand_d, cand_i, emb, zq, 16384, 32);
    apply_kernel<16, 16><<<2048, 256, 0, stream>>>(zrest, zq, out + 4 * LVL, out + 3 * LVL, nullptr, nullptr);
}